// Round 1
// 98.062 us; speedup vs baseline: 1.0380x; 1.0380x over previous
//
#include <hip/hip_runtime.h>
#include <hip/hip_bf16.h>
#include <stdint.h>

typedef __attribute__((ext_vector_type(8))) __bf16 bf16x8;
typedef __attribute__((ext_vector_type(16))) float floatx16;

#if __has_builtin(__builtin_amdgcn_exp2f)
#define EXP2F(x) __builtin_amdgcn_exp2f(x)
#else
#define EXP2F(x) exp2f(x)
#endif

#define GAS __attribute__((address_space(1)))
#define LAS __attribute__((address_space(3)))

// sqrt(2*log2(e)): baked into normalized rows so dot = 2*log2(e)*cos and
// sim = exp2(dot) = exp(cos/0.5) with zero epilogue multiplies.
#define SCALE_SQRT 1.69864359f
#define JCH 8  // j-chunks; grid = 64 strips x 8 chunks = 512 blocks = 2/CU

// ---------------- prep: int64-probe labels + normalize -----------------------
__global__ __launch_bounds__(256) void k_prep(const float* __restrict__ x,
                                              const int* __restrict__ raw,
                                              ushort* __restrict__ xb,
                                              int* __restrict__ lab, int N) {
  const int row = (blockIdx.x * 256 + threadIdx.x) >> 6;  // one wave per row
  const int lane = threadIdx.x & 63;
  if (row >= N) return;
  // parallel int64 detection: odd words all zero => labels are int64
  const int probe = raw[2 * lane + 1];
  const bool is64 = (__ballot(probe != 0) == 0ull);
  const float2 v = ((const float2*)(x + (size_t)row * 128))[lane];
  float ss = v.x * v.x + v.y * v.y;
#pragma unroll
  for (int m = 1; m < 64; m <<= 1) ss += __shfl_xor(ss, m, 64);
  const float rn = SCALE_SQRT / fmaxf(sqrtf(ss), 1e-12f);
  __hip_bfloat162 o;
  o.x = __float2bfloat16(v.x * rn);
  o.y = __float2bfloat16(v.y * rn);
  ((__hip_bfloat162*)xb)[row * 64 + lane] = o;
  if (lane == 0) lab[row] = is64 ? raw[2 * row] : raw[row];
}

// ---------------- main: full-matrix tiled exp(x x^T/T) row sums --------------
// grid (JCH, N/128). Block: 256 thr = 4 waves; each wave owns a 32-row band of
// the 128-row strip and ALL 64 cols of each j-tile (2 mfma per kt).
// A fragments: loaded ONCE from global (xb is 2 MB -> L2-resident) into 32
// VGPRs per wave; no ldsA at all. Only B is LDS-staged (2x16 KB dbuf via
// global_load_lds with XOR-16 source permute). One barrier per tile.
__global__ __launch_bounds__(256, 2) void k_sim(const ushort* __restrict__ xb,
                                                const int* __restrict__ lab,
                                                float* __restrict__ pneg,
                                                float* __restrict__ ppos,
                                                int N, int jpb) {
  __shared__ ushort ldsB[2][64 * 128];  // 2 x 16 KB
  const int tid = threadIdx.x;
  const int lane = tid & 63;
  const int wv = tid >> 6;
  const int l31 = lane & 31, g2 = lane >> 5;
  const int l15 = lane & 15, g4 = lane >> 4;
  const int i0 = blockIdx.y * 128;
  const int c = blockIdx.x;
  const int jt0 = c * jpb;

  // ---- stage first B tile ----
  {
    const int j0 = jt0 * 64;
#pragma unroll
    for (int it = 0; it < 4; ++it) {
      const int r0 = it * 16 + wv * 4;  // wave-uniform LDS row base
      const int lr = r0 + g4;
      const int kb = l15 ^ (lr & 15);
      const ushort* gp = xb + (size_t)(j0 + lr) * 128 + kb * 8;
      __builtin_amdgcn_global_load_lds((GAS void*)gp, (LAS void*)&ldsB[0][r0 * 128], 16, 0, 0);
    }
  }

  // ---- A fragments straight from global (L2-hot): rows wv*32+l31 ----
  const int arow = i0 + wv * 32 + l31;
  bf16x8 af[8];
#pragma unroll
  for (int kt = 0; kt < 8; ++kt)
    af[kt] = *(const bf16x8*)(xb + (size_t)arow * 128 + (kt * 2 + g2) * 8);

  // per-lane row labels + accumulators (C/D 32x32: col=lane&31,
  // row = (reg&3) + 8*(reg>>2) + 4*(lane>>5))
  int li[16];
  float neg[16], pos[16];
#pragma unroll
  for (int r = 0; r < 16; ++r) {
    li[r] = lab[i0 + wv * 32 + (r & 3) + 8 * (r >> 2) + 4 * g2];
    neg[r] = 0.0f;
    pos[r] = 0.0f;
  }
  __syncthreads();  // B0 staged (vmcnt drained per wave at barrier)

  for (int t = 0; t < jpb; ++t) {
    const int j0 = (jt0 + t) * 64;
    const int buf = t & 1;
    if (t + 1 < jpb) {  // prefetch next B into other buffer; lands during compute
      const int jn = j0 + 64;
#pragma unroll
      for (int it = 0; it < 4; ++it) {
        const int r0 = it * 16 + wv * 4;
        const int lr = r0 + g4;
        const int kb = l15 ^ (lr & 15);
        const ushort* gp = xb + (size_t)(jn + lr) * 128 + kb * 8;
        __builtin_amdgcn_global_load_lds((GAS void*)gp, (LAS void*)&ldsB[buf ^ 1][r0 * 128], 16, 0, 0);
      }
    }
    const int lj0 = lab[j0 + l31];       // column labels, both halves
    const int lj1 = lab[j0 + 32 + l31];

    floatx16 acc[2];
    acc[0] = (floatx16)(0.0f);
    acc[1] = (floatx16)(0.0f);
    __builtin_amdgcn_s_setprio(1);
#pragma unroll
    for (int kt = 0; kt < 8; ++kt) {
#pragma unroll
      for (int h = 0; h < 2; ++h) {
        const int brow = h * 32 + l31;
        const int bkb = (kt * 2 + g2) ^ (brow & 15);
        const bf16x8 bfr = *(const bf16x8*)&ldsB[buf][brow * 128 + bkb * 8];
        acc[h] = __builtin_amdgcn_mfma_f32_32x32x16_bf16(af[kt], bfr, acc[h], 0, 0, 0);
      }
    }
    __builtin_amdgcn_s_setprio(0);

    // ---- epilogue: exp2, diag-skip, row accumulation (registers only) ----
    const int dlt = j0 - i0;             // tile touches diagonal iff dlt in {0,64}
    const bool diag = ((unsigned)dlt < 128u);
    auto epi = [&](bool DG) {
#pragma unroll
      for (int h = 0; h < 2; ++h) {
        const int lj = h ? lj1 : lj0;
        const int jc = h * 32 + l31 + dlt;
#pragma unroll
        for (int r = 0; r < 16; ++r) {
          float e = EXP2F(acc[h][r]);
          if (DG) {
            const int ir = wv * 32 + (r & 3) + 8 * (r >> 2) + 4 * g2;
            if (ir == jc) e = 0.0f;      // exclude self-similarity exactly
          }
          neg[r] += e;
          pos[r] += (li[r] == lj) ? e : 0.0f;
        }
      }
    };
    if (diag) epi(true); else epi(false);
    __syncthreads();  // all reads of buf done; prefetch(t+1) already drained
  }

  // ---- flush: reduce over 32 col-lanes; single writer lane per row ----
#pragma unroll
  for (int r = 0; r < 16; ++r) {
    float n = neg[r], p = pos[r];
#pragma unroll
    for (int m = 1; m < 32; m <<= 1) {
      n += __shfl_xor(n, m, 64);
      p += __shfl_xor(p, m, 64);
    }
    if (l31 == 0) {
      const int row = i0 + wv * 32 + (r & 3) + 8 * (r >> 2) + 4 * g2;
      pneg[(size_t)c * N + row] = n;
      ppos[(size_t)c * N + row] = p;
    }
  }
}

// ---------------- finalize: parallel over 32 blocks, 1 row/thread ------------
__global__ __launch_bounds__(256) void k_final(const float* __restrict__ pneg,
                                               const float* __restrict__ ppos,
                                               const int* __restrict__ lab,
                                               double* __restrict__ partial, int N) {
  __shared__ int h[64];
  __shared__ double wsum[4];
  const int tid = threadIdx.x;
  if (tid < 64) h[tid] = 0;
  __syncthreads();
  for (int i = tid; i < N; i += 256) atomicAdd(&h[lab[i] & 63], 1);
  __syncthreads();
  const int r = blockIdx.x * 256 + tid;
  double v = 0.0;
  if (r < N) {
    float n = 0.0f, p = 0.0f;
#pragma unroll
    for (int cc = 0; cc < JCH; ++cc) {
      n += pneg[(size_t)cc * N + r];
      p += ppos[(size_t)cc * N + r];
    }
    const float cnt = (float)(h[lab[r] & 63] - 1);
    v = (double)logf(n * cnt / p);
  }
#pragma unroll
  for (int m = 1; m < 64; m <<= 1) v += __shfl_xor(v, m, 64);
  if ((tid & 63) == 0) wsum[tid >> 6] = v;
  __syncthreads();
  if (tid == 0) partial[blockIdx.x] = wsum[0] + wsum[1] + wsum[2] + wsum[3];
}

__global__ __launch_bounds__(64) void k_write(const double* __restrict__ partial,
                                              float* __restrict__ out, int nfb, int N) {
  const int l = threadIdx.x;
  double v = 0.0;
  for (int i = l; i < nfb; i += 64) v += partial[i];
#pragma unroll
  for (int m = 1; m < 64; m <<= 1) v += __shfl_xor(v, m, 64);
  if (l == 0) out[0] = (float)(v / (double)N);
}

extern "C" void kernel_launch(void* const* d_in, const int* in_sizes, int n_in,
                              void* d_out, int out_size, void* d_ws, size_t ws_size,
                              hipStream_t stream) {
  const float* x = (const float*)d_in[0];
  const int* raw_label = (const int*)d_in[1];
  const int N = in_sizes[1];  // 8192
  char* ws = (char*)d_ws;
  ushort* xb = (ushort*)ws;                          // N*128 bf16 = 2 MB
  float* pneg = (float*)(ws + (size_t)N * 128 * 2);  // JCH*N f32 = 256 KB
  float* ppos = pneg + (size_t)JCH * N;              // JCH*N f32 = 256 KB
  int* lab = (int*)(ppos + (size_t)JCH * N);         // N ints = 32 KB
  double* partial = (double*)(lab + N);              // <=64 doubles
  float* out = (float*)d_out;

  const int jpb = (N / 64) / JCH;   // 16 j-tiles per block
  const int nfb = (N + 255) / 256;  // 32 finalize blocks

  k_prep<<<dim3(N / 4), dim3(256), 0, stream>>>(x, raw_label, xb, lab, N);
  k_sim<<<dim3(JCH, N / 128), dim3(256), 0, stream>>>(xb, lab, pneg, ppos, N, jpb);
  k_final<<<dim3(nfb), dim3(256), 0, stream>>>(pneg, ppos, lab, partial, N);
  k_write<<<dim3(1), dim3(64), 0, stream>>>(partial, out, nfb, N);
}